// Round 6
// baseline (90.169 us; speedup 1.0000x reference)
//
#include <hip/hip_runtime.h>

#define SEQd 64
#define BATCHd 256
#define DF 40

typedef float f2 __attribute__((ext_vector_type(2)));
typedef __fp16 h2v __attribute__((ext_vector_type(2)));

// ---------------------------------------------------------------------------
// 8-qubit statevector: 8 lanes/circuit, 32 amps (f2) per lane, 8 circuits/wave.
// Amp index p (8 bits, wire j <-> bit 7-j): lam = p & 7 (lane), k = p >> 3 (reg).
// Gate masks/sign-rows are the SAME verified 8-bit constants as the passing
// 16-amp kernel; only the (lane,reg) split changes: LM=M&7, RM=M>>3.
// parity(p & SM) = parity(lam & (SM&7)) ^ parity(k & (SM>>3)) — invariant.
// ---------------------------------------------------------------------------

template<int LM>
__device__ __forceinline__ float xch1(float v) {
  if constexpr (LM == 0) {
    return v;
  } else if constexpr (LM == 1 || LM == 2 || LM == 3 || LM == 7) {
    constexpr int ctrl = (LM == 1) ? 0xB1 : (LM == 2) ? 0x4E : (LM == 3) ? 0x1B
                       : 0x141;   // 7 = row_half_mirror (xor7 within 8 lanes)
    return __int_as_float(__builtin_amdgcn_mov_dpp(__float_as_int(v), ctrl, 0xF, 0xF, true));
  } else {  // 4,5,6 -> ds_swizzle BitMode xor
    return __int_as_float(__builtin_amdgcn_ds_swizzle(__float_as_int(v), (LM << 10) | 0x1F));
  }
}

template<int LM>
__device__ __forceinline__ f2 xch2(f2 v) {
  if constexpr (LM == 0) return v;
  f2 r; r.x = xch1<LM>(v.x); r.y = xch1<LM>(v.y); return r;
}

__device__ __forceinline__ f2 ff(f2 x, f2 y, f2 z) { return __builtin_elementwise_fma(x, y, z); }
__device__ __forceinline__ f2 cmul(f2 a, f2 b) {
  f2 r; r.x = a.x * b.x - a.y * b.y; r.y = a.x * b.y + a.y * b.x; return r;
}
__device__ __forceinline__ f2 uget(float4 f, bool bit) {
  f2 r; r.x = bit ? f.z : f.x; r.y = bit ? -f.w : f.y; return r;
}

// RY: new = c*A + (parity(p&SM)? s : -s) * partner(p^M)
template<int M, int SM>
__device__ __forceinline__ void ry32(f2* a, f2 cs, int lam) {
  constexpr int LM = M & 7, RM = M >> 3, SL = SM & 7, SR = SM >> 3;
  float t0;
  if constexpr (SL != 0) t0 = (__popc(lam & SL) & 1) ? cs.y : -cs.y;
  else                   t0 = -cs.y;
  const f2 cv = {cs.x, cs.x};
  const f2 tp = {t0, t0}, tn = {-t0, -t0};
#pragma unroll
  for (int k = 0; k < 32; ++k) {
    const int kp = k ^ RM;
    if (kp < k) continue;
    if (kp == k) {
      const f2 b = xch2<LM>(a[k]);
      a[k] = ff(b, (__builtin_popcount(k & SR) & 1) ? tn : tp, a[k] * cv);
    } else {
      const f2 b0 = xch2<LM>(a[kp]);
      const f2 b1 = xch2<LM>(a[k]);
      const f2 t_k  = (__builtin_popcount(k  & SR) & 1) ? tn : tp;
      const f2 t_kp = (__builtin_popcount(kp & SR) & 1) ? tn : tp;
      a[k]  = ff(b0, t_k,  a[k]  * cv);
      a[kp] = ff(b1, t_kp, a[kp] * cv);
    }
  }
}

// Fused U = RY(ty)*RX(tx), q=(a,b,c2,d)=(cy*cx, sy*sx, sy*cx, cy*sx).
// r = qa*A - fc*B + fb*J(A) - qw*J(B); J(v)=(-v.y,v.x); fb,fc sign by parity.
template<int M, int SM>
__device__ __forceinline__ void su2_32(f2* a, float4 q, int lam) {
  constexpr int LM = M & 7, RM = M >> 3, SL = SM & 7, SR = SM >> 3;
  float sb, sc;
  if constexpr (SL != 0) {
    const bool p = (__popc(lam & SL) & 1) != 0;
    sb = p ? -q.y : q.y; sc = p ? -q.z : q.z;
  } else { sb = q.y; sc = q.z; }
  const f2 vqa = {q.x, q.x};
  const f2 vqw = {q.w, -q.w};
  const f2 vfc0 = {-sc, -sc}, vfb0 = {-sb, sb};
  const f2 vfc1 = { sc,  sc}, vfb1 = { sb, -sb};
#pragma unroll
  for (int k = 0; k < 32; ++k) {
    const int kp = k ^ RM;
    if (kp < k) continue;
    if (kp == k) {
      const f2 B = xch2<LM>(a[k]);
      const bool pk = (__builtin_popcount(k & SR) & 1) != 0;
      const f2 A = a[k];
      f2 r = A * vqa;
      r = ff(B, pk ? vfc1 : vfc0, r);
      r = ff(A.yx, pk ? vfb1 : vfb0, r);
      r = ff(B.yx, vqw, r);
      a[k] = r;
    } else {
      const f2 B0 = xch2<LM>(a[kp]);
      const f2 B1 = xch2<LM>(a[k]);
      const bool pk0 = (__builtin_popcount(k  & SR) & 1) != 0;
      const bool pk1 = (__builtin_popcount(kp & SR) & 1) != 0;
      const f2 A0 = a[k], A1 = a[kp];
      f2 r0 = A0 * vqa;
      r0 = ff(B0, pk0 ? vfc1 : vfc0, r0);
      r0 = ff(A0.yx, pk0 ? vfb1 : vfb0, r0);
      r0 = ff(B0.yx, vqw, r0);
      a[k] = r0;
      f2 r1 = A1 * vqa;
      r1 = ff(B1, pk1 ? vfc1 : vfc0, r1);
      r1 = ff(A1.yx, pk1 ? vfb1 : vfb0, r1);
      r1 = ff(B1.yx, vqw, r1);
      a[kp] = r1;
    }
  }
}

// 3 x [ring CNOT (free GF(2) relabeling) + 8 RY]; same verified constants.
__device__ __forceinline__ void layers32(f2* a, const f2* __restrict__ L, int lam) {
  ry32<0xC0,0x7F>(a, L[0],  lam);
  ry32<0x60,0xC0>(a, L[1],  lam);
  ry32<0x30,0xE0>(a, L[2],  lam);
  ry32<0x18,0xF0>(a, L[3],  lam);
  ry32<0x0C,0xF8>(a, L[4],  lam);
  ry32<0x06,0xFC>(a, L[5],  lam);
  ry32<0x03,0xFE>(a, L[6],  lam);
  ry32<0xC1,0xFF>(a, L[7],  lam);
  ry32<0xA0,0xD5>(a, L[8],  lam);
  ry32<0x50,0xBF>(a, L[9],  lam);
  ry32<0x28,0x5F>(a, L[10], lam);
  ry32<0x14,0xAF>(a, L[11], lam);
  ry32<0x0A,0x57>(a, L[12], lam);
  ry32<0x05,0xAB>(a, L[13], lam);
  ry32<0xC2,0x55>(a, L[14], lam);
  ry32<0x61,0xAA>(a, L[15], lam);
  ry32<0xF0,0x4C>(a, L[16], lam);
  ry32<0x78,0x6A>(a, L[17], lam);
  ry32<0x3C,0x35>(a, L[18], lam);
  ry32<0x1E,0x9A>(a, L[19], lam);
  ry32<0x0F,0xCD>(a, L[20], lam);
  ry32<0xC7,0x66>(a, L[21], lam);
  ry32<0xA3,0x33>(a, L[22], lam);
  ry32<0x91,0x99>(a, L[23], lam);
}

// initial fused RX*RY on all 8 wires (variational halves; F0 = I)
__device__ __forceinline__ void initial32(f2* a, const float4* __restrict__ F, int lam) {
  su2_32<0x80,0x80>(a, F[0], lam);
  su2_32<0x40,0x40>(a, F[1], lam);
  su2_32<0x20,0x20>(a, F[2], lam);
  su2_32<0x10,0x10>(a, F[3], lam);
  su2_32<0x08,0x08>(a, F[4], lam);
  su2_32<0x04,0x04>(a, F[5], lam);
  su2_32<0x02,0x02>(a, F[6], lam);
  su2_32<0x01,0x01>(a, F[7], lam);
}

// Encoding half from |0..0>: product state, zero exchanges.
// lam bit i = amp bit i = wire 7-i; k bit j = amp bit 3+j = wire 4-j.
__device__ __forceinline__ void pinit32(f2* a, const float4* __restrict__ F, int lam) {
  f2 c = {1.f, 0.f};
#pragma unroll
  for (int i = 0; i < 3; ++i)
    c = cmul(c, uget(F[7 - i], ((lam >> i) & 1) != 0));
  f2 wlo[4], whi[8];
#pragma unroll
  for (int t = 0; t < 4; ++t)
    wlo[t] = cmul(uget(F[4], (t & 1) != 0), uget(F[3], ((t >> 1) & 1) != 0));
#pragma unroll
  for (int t = 0; t < 8; ++t)
    whi[t] = cmul(cmul(uget(F[2], (t & 1) != 0), uget(F[1], ((t >> 1) & 1) != 0)),
                  uget(F[0], ((t >> 2) & 1) != 0));
#pragma unroll
  for (int k = 0; k < 32; ++k)
    a[k] = cmul(cmul(c, wlo[k & 3]), whi[k >> 2]);
}

__device__ __forceinline__ uint32_t packh(f2 v) {
  h2v h = __builtin_amdgcn_cvt_pkrtz(v.x, v.y);
  return __builtin_bit_cast(uint32_t, h);
}
__device__ __forceinline__ f2 unpackh(uint32_t u) {
  h2v h = __builtin_bit_cast(h2v, u);
  f2 r; r.x = (float)h[0]; r.y = (float)h[1]; return r;
}

// snapshot: value at slot p stored at address F3*p, laid out so the re-read
// is linear: sidx(q) = ((q&7)<<5) | (q>>3)  (lam-major, 32 consecutive per lam)
__device__ __forceinline__ void snap_write32(const f2* a, uint32_t* sn, int lam) {
  int tgt = 0;                       // F3 columns for amp bits 0..2 (lane bits)
  if (lam & 1) tgt ^= 0x2B;
  if (lam & 2) tgt ^= 0x56;
  if (lam & 4) tgt ^= 0xAC;
#pragma unroll
  for (int k = 0; k < 32; ++k) {     // F3 columns for amp bits 3..7 (reg bits)
    const int rck = ((k & 1) ? 0xD9 : 0) ^ ((k & 2) ? 0x33 : 0) ^ ((k & 4) ? 0x66 : 0)
                  ^ ((k & 8) ? 0xCC : 0) ^ ((k & 16) ? 0x19 : 0);
    const int qq = tgt ^ rck;
    sn[((qq & 7) << 5) | (qq >> 3)] = packh(a[k]);
  }
}

__device__ __forceinline__ void snap_read32(f2* a, const uint32_t* sn, int lam) {
  const uint4* p = (const uint4*)(sn + lam * 32);
#pragma unroll
  for (int t = 0; t < 8; ++t) {
    const uint4 w = p[t];
    a[4*t+0] = unpackh(w.x); a[4*t+1] = unpackh(w.y);
    a[4*t+2] = unpackh(w.z); a[4*t+3] = unpackh(w.w);
  }
}

// <Z...>: Z0 -> SM 0x4C; Zall -> SM 0x88 (F3 rows; unchanged constants)
template<int SM>
__device__ __forceinline__ float expect32(const f2* a, int lam) {
  constexpr int SL = SM & 7, SR = SM >> 3;
  float s0 = 0.f, s1 = 0.f;
#pragma unroll
  for (int k = 0; k < 32; ++k) {
    const float p = a[k].x * a[k].x + a[k].y * a[k].y;
    if ((__builtin_popcount(k & SR) & 1) != 0) s1 += p; else s0 += p;
  }
  const float d = s0 - s1;
  float v;
  if constexpr (SL != 0) v = (__popc(lam & SL) & 1) ? -d : d;
  else                   v = d;
  v += xch1<1>(v); v += xch1<2>(v); v += xch1<4>(v);
  return v;
}

// per-(s,half) variational coefficient tables: 80 floats = 8*float4 + 24*float2
__global__ __launch_bounds__(256) void prep_var(
    const float* __restrict__ pQ, const float* __restrict__ pK,
    const float* __restrict__ pV, float* __restrict__ vtab)
{
  const int t = blockIdx.x * 256 + threadIdx.x;
  if (t >= SEQd * 3 * 32) return;
  const int slot = t & 31;
  const int sh = t >> 5;
  const int h = sh % 3, sp = sh / 3;
  const float* w = ((h == 0) ? pQ : (h == 1) ? pK : pV) + sp * DF;
  float* o = vtab + sh * 80;
  if (slot < 8) {
    float cx, sx, cy, sy;
    __sincosf(w[2 * slot]     * 0.5f, &sx, &cx);
    __sincosf(w[2 * slot + 1] * 0.5f, &sy, &cy);
    ((float4*)o)[slot] = make_float4(cy * cx, sy * sx, sy * cx, cy * sx);
  } else {
    float sn, cn;
    __sincosf(w[16 + (slot - 8)] * 0.5f, &sn, &cn);
    ((float2*)(o + 32))[slot - 8] = make_float2(cn, sn);
  }
}

// Block = 256 threads = 4 waves, 8 circuits (all same s).
// wave 0: encoding + snapshot (then retires). waves 1..3: one var half each,
// coefs via block-uniform scalar loads from global.
__global__ __launch_bounds__(256) void qsal_circuits(
    const float* __restrict__ x, const float* __restrict__ vtab,
    float* __restrict__ Qo, float* __restrict__ Ko, float* __restrict__ Vo)
{
  __shared__ __align__(16) float etab[8][84];       // pad 84: distinct banks per circuit
  __shared__ __align__(16) uint32_t snap[8][264];   // fp16-packed snapshot per circuit
  const int tid = threadIdx.x;
  const int wid = tid >> 6, lane = tid & 63;
  const int ci = lane >> 3, lam = lane & 7;
  const int s = blockIdx.x & 63;
  const int bbase = (blockIdx.x >> 6) << 3;

  // fill enc coef tables: 8 circuits x 40 angles
  for (int t = tid; t < 320; t += 256) {
    const int cc = t / 40, idx = t - cc * 40;
    const float ang = x[((size_t)(bbase + cc) * 64 + s) * 40 + idx];
    float sn, cn; __sincosf(ang * 0.5f, &sn, &cn);
    if (idx < 16) {
      const int wire = idx >> 1, isy = idx & 1;
      etab[cc][wire * 4 + isy * 2 + 0] = cn;
      etab[cc][wire * 4 + isy * 2 + 1] = sn;
    } else {
      etab[cc][32 + (idx - 16) * 2 + 0] = cn;
      etab[cc][32 + (idx - 16) * 2 + 1] = sn;
    }
  }
  __syncthreads();
  if (tid < 64) {   // fold (cx,sx,cy,sy) -> (a,b,c2,d)
    const int cc = tid >> 3, wire = tid & 7;
    float4* qt = (float4*)etab[cc];
    const float4 f = qt[wire];
    qt[wire] = make_float4(f.z * f.x, f.w * f.y, f.w * f.x, f.z * f.y);
  }
  __syncthreads();

  if (wid == 0) {
    f2 a[32];
    pinit32(a, (const float4*)etab[ci], lam);
    layers32(a, (const f2*)(etab[ci] + 32), lam);
    snap_write32(a, snap[ci], lam);
  }
  __syncthreads();

  if (wid >= 1) {
    const int h = wid - 1;
    const float* th = vtab + s * 240 + 80 * h;     // block-uniform -> scalar loads
    f2 v[32];
    snap_read32(v, snap[ci], lam);
    initial32(v, (const float4*)th, lam);
    layers32(v, (const f2*)(th + 32), lam);
    const float e = (h == 2) ? expect32<0x88>(v, lam) : expect32<0x4C>(v, lam);
    if (lam == 0) {
      float* op = (h == 0) ? Qo : (h == 1) ? Ko : Vo;
      op[(bbase + ci) * 64 + s] = e;
    }
  }
}

__global__ __launch_bounds__(256) void qsal_attn(
    const float* __restrict__ x,
    const float* __restrict__ Qv,
    const float* __restrict__ Kv,
    const float* __restrict__ Vv,
    float* __restrict__ out)
{
  const int tid  = threadIdx.x;
  const int wid  = tid >> 6;
  const int lane = tid & 63;                 // m
  const int bi   = blockIdx.x * 4 + wid;     // b*64 + i
  const int b    = bi >> 6;

  const float q = Qv[bi];
  const float k = Kv[b * 64 + lane];
  const float v = Vv[b * 64 + lane];
  const float d = q - k;
  float e  = __expf(-d * d);
  float ev = e * v;
#pragma unroll
  for (int m = 1; m < 64; m <<= 1) {
    e  += __shfl_xor(e,  m, 64);
    ev += __shfl_xor(ev, m, 64);
  }
  const float att = ev / e;

  const size_t row = (size_t)bi * DF;
  if (lane < DF) out[row + lane] = x[row + lane] + att;
}

extern "C" void kernel_launch(void* const* d_in, const int* in_sizes, int n_in,
                              void* d_out, int out_size, void* d_ws, size_t ws_size,
                              hipStream_t stream) {
  const float* x  = (const float*)d_in[0];
  const float* pQ = (const float*)d_in[1];
  const float* pK = (const float*)d_in[2];
  const float* pV = (const float*)d_in[3];
  float* out = (float*)d_out;

  float* Qv   = (float*)d_ws;                    // [16384]
  float* Kv   = Qv + BATCHd * SEQd;
  float* Vv   = Kv + BATCHd * SEQd;
  float* vtab = Vv + BATCHd * SEQd;              // [64*3*80]

  prep_var<<<dim3(24), dim3(256), 0, stream>>>(pQ, pK, pV, vtab);
  qsal_circuits<<<dim3(2048), dim3(256), 0, stream>>>(x, vtab, Qv, Kv, Vv);
  qsal_attn<<<dim3(BATCHd * SEQd / 4), dim3(256), 0, stream>>>(x, Qv, Kv, Vv, out);
}

// Round 7
// 76.895 us; speedup vs baseline: 1.1726x; 1.1726x over previous
//
#include <hip/hip_runtime.h>

#define SEQd 64
#define BATCHd 256
#define DF 40

typedef float f2 __attribute__((ext_vector_type(2)));
typedef __fp16 h2v __attribute__((ext_vector_type(2)));

// ---------------------------------------------------------------------------
// 8-qubit statevector: 8 lanes/circuit, 32 amps (f2) per lane, 8 circuits/wave.
// Amp index p (8 bits, wire j <-> bit 7-j): lam = p & 7 (lane), k = p >> 3 (reg).
// Gate masks/sign-rows are the SAME verified 8-bit constants as the passing
// kernels; split LM=M&7 (lane), RM=M>>3 (reg).
// Monolithic waves: every wave does enc + snapshot + 3 var halves for its own
// 8 circuits (no cross-wave dependencies; R6's wave-specialization bubbles gone).
// ---------------------------------------------------------------------------

template<int LM>
__device__ __forceinline__ float xch1(float v) {
  if constexpr (LM == 0) {
    return v;
  } else if constexpr (LM == 1 || LM == 2 || LM == 3 || LM == 7) {
    constexpr int ctrl = (LM == 1) ? 0xB1 : (LM == 2) ? 0x4E : (LM == 3) ? 0x1B
                       : 0x141;   // 7 = row_half_mirror (xor7 within 8 lanes)
    return __int_as_float(__builtin_amdgcn_mov_dpp(__float_as_int(v), ctrl, 0xF, 0xF, true));
  } else {  // 4,5,6 -> ds_swizzle BitMode xor
    return __int_as_float(__builtin_amdgcn_ds_swizzle(__float_as_int(v), (LM << 10) | 0x1F));
  }
}

template<int LM>
__device__ __forceinline__ f2 xch2(f2 v) {
  if constexpr (LM == 0) return v;
  f2 r; r.x = xch1<LM>(v.x); r.y = xch1<LM>(v.y); return r;
}

__device__ __forceinline__ f2 ff(f2 x, f2 y, f2 z) { return __builtin_elementwise_fma(x, y, z); }
__device__ __forceinline__ f2 cmul(f2 a, f2 b) {
  f2 r; r.x = a.x * b.x - a.y * b.y; r.y = a.x * b.y + a.y * b.x; return r;
}
__device__ __forceinline__ f2 uget(float4 f, bool bit) {
  f2 r; r.x = bit ? f.z : f.x; r.y = bit ? -f.w : f.y; return r;
}

// RY: new = c*A + (parity(p&SM)? s : -s) * partner(p^M)
template<int M, int SM>
__device__ __forceinline__ void ry32(f2* a, f2 cs, int lam) {
  constexpr int LM = M & 7, RM = M >> 3, SL = SM & 7, SR = SM >> 3;
  float t0;
  if constexpr (SL != 0) t0 = (__popc(lam & SL) & 1) ? cs.y : -cs.y;
  else                   t0 = -cs.y;
  const f2 cv = {cs.x, cs.x};
  const f2 tp = {t0, t0}, tn = {-t0, -t0};
#pragma unroll
  for (int k = 0; k < 32; ++k) {
    const int kp = k ^ RM;
    if (kp < k) continue;
    if (kp == k) {
      const f2 b = xch2<LM>(a[k]);
      a[k] = ff(b, (__builtin_popcount(k & SR) & 1) ? tn : tp, a[k] * cv);
    } else {
      const f2 b0 = xch2<LM>(a[kp]);
      const f2 b1 = xch2<LM>(a[k]);
      const f2 t_k  = (__builtin_popcount(k  & SR) & 1) ? tn : tp;
      const f2 t_kp = (__builtin_popcount(kp & SR) & 1) ? tn : tp;
      a[k]  = ff(b0, t_k,  a[k]  * cv);
      a[kp] = ff(b1, t_kp, a[kp] * cv);
    }
  }
}

// Fused U = RY(ty)*RX(tx), q=(a,b,c2,d)=(cy*cx, sy*sx, sy*cx, cy*sx).
template<int M, int SM>
__device__ __forceinline__ void su2_32(f2* a, float4 q, int lam) {
  constexpr int LM = M & 7, RM = M >> 3, SL = SM & 7, SR = SM >> 3;
  float sb, sc;
  if constexpr (SL != 0) {
    const bool p = (__popc(lam & SL) & 1) != 0;
    sb = p ? -q.y : q.y; sc = p ? -q.z : q.z;
  } else { sb = q.y; sc = q.z; }
  const f2 vqa = {q.x, q.x};
  const f2 vqw = {q.w, -q.w};
  const f2 vfc0 = {-sc, -sc}, vfb0 = {-sb, sb};
  const f2 vfc1 = { sc,  sc}, vfb1 = { sb, -sb};
#pragma unroll
  for (int k = 0; k < 32; ++k) {
    const int kp = k ^ RM;
    if (kp < k) continue;
    if (kp == k) {
      const f2 B = xch2<LM>(a[k]);
      const bool pk = (__builtin_popcount(k & SR) & 1) != 0;
      const f2 A = a[k];
      f2 r = A * vqa;
      r = ff(B, pk ? vfc1 : vfc0, r);
      r = ff(A.yx, pk ? vfb1 : vfb0, r);
      r = ff(B.yx, vqw, r);
      a[k] = r;
    } else {
      const f2 B0 = xch2<LM>(a[kp]);
      const f2 B1 = xch2<LM>(a[k]);
      const bool pk0 = (__builtin_popcount(k  & SR) & 1) != 0;
      const bool pk1 = (__builtin_popcount(kp & SR) & 1) != 0;
      const f2 A0 = a[k], A1 = a[kp];
      f2 r0 = A0 * vqa;
      r0 = ff(B0, pk0 ? vfc1 : vfc0, r0);
      r0 = ff(A0.yx, pk0 ? vfb1 : vfb0, r0);
      r0 = ff(B0.yx, vqw, r0);
      a[k] = r0;
      f2 r1 = A1 * vqa;
      r1 = ff(B1, pk1 ? vfc1 : vfc0, r1);
      r1 = ff(A1.yx, pk1 ? vfb1 : vfb0, r1);
      r1 = ff(B1.yx, vqw, r1);
      a[kp] = r1;
    }
  }
}

// 3 x [ring CNOT (free GF(2) relabeling) + 8 RY]; same verified constants.
__device__ __forceinline__ void layers32(f2* a, const f2* __restrict__ L, int lam) {
  ry32<0xC0,0x7F>(a, L[0],  lam);
  ry32<0x60,0xC0>(a, L[1],  lam);
  ry32<0x30,0xE0>(a, L[2],  lam);
  ry32<0x18,0xF0>(a, L[3],  lam);
  ry32<0x0C,0xF8>(a, L[4],  lam);
  ry32<0x06,0xFC>(a, L[5],  lam);
  ry32<0x03,0xFE>(a, L[6],  lam);
  ry32<0xC1,0xFF>(a, L[7],  lam);
  ry32<0xA0,0xD5>(a, L[8],  lam);
  ry32<0x50,0xBF>(a, L[9],  lam);
  ry32<0x28,0x5F>(a, L[10], lam);
  ry32<0x14,0xAF>(a, L[11], lam);
  ry32<0x0A,0x57>(a, L[12], lam);
  ry32<0x05,0xAB>(a, L[13], lam);
  ry32<0xC2,0x55>(a, L[14], lam);
  ry32<0x61,0xAA>(a, L[15], lam);
  ry32<0xF0,0x4C>(a, L[16], lam);
  ry32<0x78,0x6A>(a, L[17], lam);
  ry32<0x3C,0x35>(a, L[18], lam);
  ry32<0x1E,0x9A>(a, L[19], lam);
  ry32<0x0F,0xCD>(a, L[20], lam);
  ry32<0xC7,0x66>(a, L[21], lam);
  ry32<0xA3,0x33>(a, L[22], lam);
  ry32<0x91,0x99>(a, L[23], lam);
}

// initial fused RX*RY on all 8 wires (variational halves; F0 = I)
__device__ __forceinline__ void initial32(f2* a, const float4* __restrict__ F, int lam) {
  su2_32<0x80,0x80>(a, F[0], lam);
  su2_32<0x40,0x40>(a, F[1], lam);
  su2_32<0x20,0x20>(a, F[2], lam);
  su2_32<0x10,0x10>(a, F[3], lam);
  su2_32<0x08,0x08>(a, F[4], lam);
  su2_32<0x04,0x04>(a, F[5], lam);
  su2_32<0x02,0x02>(a, F[6], lam);
  su2_32<0x01,0x01>(a, F[7], lam);
}

// Encoding half from |0..0>: product state, zero exchanges.
__device__ __forceinline__ void pinit32(f2* a, const float4* __restrict__ F, int lam) {
  f2 c = {1.f, 0.f};
#pragma unroll
  for (int i = 0; i < 3; ++i)
    c = cmul(c, uget(F[7 - i], ((lam >> i) & 1) != 0));
  f2 wlo[4], whi[8];
#pragma unroll
  for (int t = 0; t < 4; ++t)
    wlo[t] = cmul(uget(F[4], (t & 1) != 0), uget(F[3], ((t >> 1) & 1) != 0));
#pragma unroll
  for (int t = 0; t < 8; ++t)
    whi[t] = cmul(cmul(uget(F[2], (t & 1) != 0), uget(F[1], ((t >> 1) & 1) != 0)),
                  uget(F[0], ((t >> 2) & 1) != 0));
#pragma unroll
  for (int k = 0; k < 32; ++k)
    a[k] = cmul(cmul(c, wlo[k & 3]), whi[k >> 2]);
}

__device__ __forceinline__ uint32_t packh(f2 v) {
  h2v h = __builtin_amdgcn_cvt_pkrtz(v.x, v.y);
  return __builtin_bit_cast(uint32_t, h);
}
__device__ __forceinline__ f2 unpackh(uint32_t u) {
  h2v h = __builtin_bit_cast(h2v, u);
  f2 r; r.x = (float)h[0]; r.y = (float)h[1]; return r;
}

// snapshot: value at slot p stored at address F3*p (resets relabeling to I).
// Layout: word index = (q&7)*36 + (q>>3); per-lam stride 36 (bank +4/lam),
// per-circuit stride 296 (bank +8) -> 2 lanes/bank on b128 reads = free.
__device__ __forceinline__ void snap_write32(const f2* a, uint32_t* sn, int lam) {
  int tgt = 0;                       // F3 columns for amp bits 0..2 (lane bits)
  if (lam & 1) tgt ^= 0x2B;
  if (lam & 2) tgt ^= 0x56;
  if (lam & 4) tgt ^= 0xAC;
#pragma unroll
  for (int k = 0; k < 32; ++k) {     // F3 columns for amp bits 3..7 (reg bits)
    const int rck = ((k & 1) ? 0xD9 : 0) ^ ((k & 2) ? 0x33 : 0) ^ ((k & 4) ? 0x66 : 0)
                  ^ ((k & 8) ? 0xCC : 0) ^ ((k & 16) ? 0x19 : 0);
    const int qq = tgt ^ rck;
    sn[(qq & 7) * 36 + (qq >> 3)] = packh(a[k]);
  }
}

__device__ __forceinline__ void snap_read32(f2* a, const uint32_t* sn, int lam) {
  const uint4* p = (const uint4*)(sn + lam * 36);
#pragma unroll
  for (int t = 0; t < 8; ++t) {
    const uint4 w = p[t];
    a[4*t+0] = unpackh(w.x); a[4*t+1] = unpackh(w.y);
    a[4*t+2] = unpackh(w.z); a[4*t+3] = unpackh(w.w);
  }
}

// <Z...>: Z0 -> SM 0x4C; Zall -> SM 0x88 (F3 rows; unchanged constants)
template<int SM>
__device__ __forceinline__ float expect32(const f2* a, int lam) {
  constexpr int SL = SM & 7, SR = SM >> 3;
  float s0 = 0.f, s1 = 0.f;
#pragma unroll
  for (int k = 0; k < 32; ++k) {
    const float p = a[k].x * a[k].x + a[k].y * a[k].y;
    if ((__builtin_popcount(k & SR) & 1) != 0) s1 += p; else s0 += p;
  }
  const float d = s0 - s1;
  float v;
  if constexpr (SL != 0) v = (__popc(lam & SL) & 1) ? -d : d;
  else                   v = d;
  v += xch1<1>(v); v += xch1<2>(v); v += xch1<4>(v);
  return v;
}

// per-(s,half) variational coefficient tables: 80 floats = 8*float4 + 24*float2
__global__ __launch_bounds__(256) void prep_var(
    const float* __restrict__ pQ, const float* __restrict__ pK,
    const float* __restrict__ pV, float* __restrict__ vtab)
{
  const int t = blockIdx.x * 256 + threadIdx.x;
  if (t >= SEQd * 3 * 32) return;
  const int slot = t & 31;
  const int sh = t >> 5;
  const int h = sh % 3, sp = sh / 3;
  const float* w = ((h == 0) ? pQ : (h == 1) ? pK : pV) + sp * DF;
  float* o = vtab + sh * 80;
  if (slot < 8) {
    float cx, sx, cy, sy;
    __sincosf(w[2 * slot]     * 0.5f, &sx, &cx);
    __sincosf(w[2 * slot + 1] * 0.5f, &sy, &cy);
    ((float4*)o)[slot] = make_float4(cy * cx, sy * sx, sy * cx, cy * sx);
  } else {
    float sn, cn;
    __sincosf(w[16 + (slot - 8)] * 0.5f, &sn, &cn);
    ((float2*)(o + 32))[slot - 8] = make_float2(cn, sn);
  }
}

// Block = 256 threads = 4 independent waves = 32 circuits (all same s).
// Every wave: enc + snapshot + 3 var halves. Single rolled phase loop
// (one layers32 instance -> fits I-cache).
__global__ __launch_bounds__(256, 3) void qsal_circuits(
    const float* __restrict__ x, const float* __restrict__ vtab,
    float* __restrict__ Qo, float* __restrict__ Ko, float* __restrict__ Vo)
{
  __shared__ __align__(16) float etab[32][84];
  __shared__ __align__(16) uint32_t snap[32][296];
  __shared__ __align__(16) float vtabs[240];
  const int tid = threadIdx.x;
  const int wid = tid >> 6, lane = tid & 63;
  const int lam = lane & 7;
  const int cig = (wid << 3) | (lane >> 3);
  const int s = blockIdx.x & 63;
  const int bbase = (blockIdx.x >> 6) << 5;

  // fill enc coef tables: 32 circuits x 40 angles
  for (int t = tid; t < 1280; t += 256) {
    const int cc = t / 40, idx = t - cc * 40;
    const float ang = x[((size_t)(bbase + cc) * 64 + s) * 40 + idx];
    float sn, cn; __sincosf(ang * 0.5f, &sn, &cn);
    if (idx < 16) {
      const int wire = idx >> 1, isy = idx & 1;
      etab[cc][wire * 4 + isy * 2 + 0] = cn;
      etab[cc][wire * 4 + isy * 2 + 1] = sn;
    } else {
      etab[cc][32 + (idx - 16) * 2 + 0] = cn;
      etab[cc][32 + (idx - 16) * 2 + 1] = sn;
    }
  }
  // var coefs (block-uniform s) into LDS
  if (tid < 60) ((float4*)vtabs)[tid] = ((const float4*)(vtab + s * 240))[tid];
  __syncthreads();
  {  // fold enc (cx,sx,cy,sy) -> (a,b,c2,d): 32 circuits x 8 wires = 256
    const int cc = tid >> 3, wire = tid & 7;
    float4* qt = (float4*)etab[cc];
    const float4 f = qt[wire];
    qt[wire] = make_float4(f.z * f.x, f.w * f.y, f.w * f.x, f.z * f.y);
  }
  __syncthreads();

  f2 st[32];
#pragma unroll 1
  for (int ph = 0; ph < 4; ++ph) {
    const f2* L;
    if (ph == 0) {
      pinit32(st, (const float4*)etab[cig], lam);
      L = (const f2*)(etab[cig] + 32);
    } else {
      snap_read32(st, snap[cig], lam);
      const float* th = vtabs + (ph - 1) * 80;
      initial32(st, (const float4*)th, lam);
      L = (const f2*)(th + 32);
    }
    layers32(st, L, lam);
    if (ph == 0) {
      snap_write32(st, snap[cig], lam);
    } else {
      const float e = (ph == 3) ? expect32<0x88>(st, lam) : expect32<0x4C>(st, lam);
      if (lam == 0) {
        float* op = (ph == 1) ? Qo : (ph == 2) ? Ko : Vo;
        op[(bbase + cig) * 64 + s] = e;
      }
    }
    __syncthreads();
  }
}

__global__ __launch_bounds__(256) void qsal_attn(
    const float* __restrict__ x,
    const float* __restrict__ Qv,
    const float* __restrict__ Kv,
    const float* __restrict__ Vv,
    float* __restrict__ out)
{
  const int tid  = threadIdx.x;
  const int wid  = tid >> 6;
  const int lane = tid & 63;                 // m
  const int bi   = blockIdx.x * 4 + wid;     // b*64 + i
  const int b    = bi >> 6;

  const float q = Qv[bi];
  const float k = Kv[b * 64 + lane];
  const float v = Vv[b * 64 + lane];
  const float d = q - k;
  float e  = __expf(-d * d);
  float ev = e * v;
#pragma unroll
  for (int m = 1; m < 64; m <<= 1) {
    e  += __shfl_xor(e,  m, 64);
    ev += __shfl_xor(ev, m, 64);
  }
  const float att = ev / e;

  const size_t row = (size_t)bi * DF;
  if (lane < DF) out[row + lane] = x[row + lane] + att;
}

extern "C" void kernel_launch(void* const* d_in, const int* in_sizes, int n_in,
                              void* d_out, int out_size, void* d_ws, size_t ws_size,
                              hipStream_t stream) {
  const float* x  = (const float*)d_in[0];
  const float* pQ = (const float*)d_in[1];
  const float* pK = (const float*)d_in[2];
  const float* pV = (const float*)d_in[3];
  float* out = (float*)d_out;

  float* Qv   = (float*)d_ws;                    // [16384]
  float* Kv   = Qv + BATCHd * SEQd;
  float* Vv   = Kv + BATCHd * SEQd;
  float* vtab = Vv + BATCHd * SEQd;              // [64*3*80]

  prep_var<<<dim3(24), dim3(256), 0, stream>>>(pQ, pK, pV, vtab);
  qsal_circuits<<<dim3(512), dim3(256), 0, stream>>>(x, vtab, Qv, Kv, Vv);
  qsal_attn<<<dim3(BATCHd * SEQd / 4), dim3(256), 0, stream>>>(x, Qv, Kv, Vv, out);
}